// Round 3
// baseline (2196.114 us; speedup 1.0000x reference)
//
#include <hip/hip_runtime.h>

// StateSpaceModel: y = scan(h = h@A + x@B) @ C,  B=32 L=2048 D=512 (fp32 io).
// Convolution formulation (no sequential recurrence anywhere):
//   y_t (t=8c+j) = sum_{d=0..j} x_{t-d} @ (B A^d C)  +  g_c @ (A^{j+1} C)
//   s_c          = sum_{i=0..7} x_{8c+i} @ (B A^{7-i})
//   g_c = H_{c-1}, H = radix-4 Kogge-Stone prefix over s with T = A^8.
// All 512x512 helper matrices precomputed in a slotted workspace.

using bf16 = __bf16;
typedef __bf16 bf16x8 __attribute__((ext_vector_type(8)));
typedef float  f32x4  __attribute__((ext_vector_type(4)));

constexpr int Dm   = 512;
constexpr int Lseq = 2048;
constexpr int Bb   = 32;
constexpr int KC   = 8;
constexpr int CH   = 256;
constexpr long SLOT = (long)Dm * Dm;

// workspace matrix slots (each 512x512 bf16 = 512 KB)
#define S_At  0   // A^T
#define S_Abf 1   // A  (= P_1)
#define S_Bbf 2   // B  (= W_0)
#define S_Bt  3   // B^T (= Wt_0)
#define S_Ct  4   // C^T
#define S_P   5   // P_d = A^d, d=2..8  -> S_P + d-2      (normal)
#define S_Pt  12  // transposed P_d                        (= S_P slot + 7)
#define S_W   19  // W_d = B A^d, d=1..7 -> S_W + d-1      (normal)
#define S_Wt  26  // transposed W_d                        (= S_W slot + 7)
#define S_T   33  // T^(2^k), k=1..7 -> S_T + k-1          (T = A^8)
#define S_Tt  40  // transposed                            (= S_T slot + 7)
#define S_X   47  // T^3t, T^12t, T^48t, T^192t (transposed only)
#define S_M   51  // Mt'_d = (B A^d C)^T, d=0..7
#define S_G   59  // Gt_j  = (A^{j+1} C)^T, j=0..7
#define NSLOT 67

__device__ __forceinline__ bf16x8 ld8(const bf16* p) {
  return *reinterpret_cast<const bf16x8*>(p);
}
__device__ __forceinline__ bf16x8 zero8() {
  bf16x8 r;
#pragma unroll
  for (int q = 0; q < 8; ++q) r[q] = (bf16)0.f;
  return r;
}
__device__ __forceinline__ f32x4 mfma16(bf16x8 a, bf16x8 b, f32x4 c) {
  return __builtin_amdgcn_mfma_f32_16x16x32_bf16(a, b, c, 0, 0, 0);
}

// ---- pack fp32 inputs -> bf16 slots: At, Abf, Bbf, Bt, Ct ----
__global__ __launch_bounds__(256) void kt_pack(
    const float* __restrict__ a, const float* __restrict__ b,
    const float* __restrict__ c, bf16* __restrict__ Wm) {
  int flat = blockIdx.x * 256 + threadIdx.x;
  int n = flat & (Dm - 1);
  int k = flat >> 9;
  const float* s = (blockIdx.y == 0) ? a : (blockIdx.y == 1) ? b : c;
  float v = s[(long)k * Dm + n];
  int tslot = (blockIdx.y == 0) ? S_At : (blockIdx.y == 1) ? S_Bt : S_Ct;
  Wm[(long)tslot * SLOT + (long)n * Dm + k] = (bf16)v;
  if (blockIdx.y == 0) Wm[(long)S_Abf * SLOT + (long)k * Dm + n] = (bf16)v;
  if (blockIdx.y == 1) Wm[(long)S_Bbf * SLOT + (long)k * Dm + n] = (bf16)v;
}

// ---- x fp32 -> bf16 ----
__global__ __launch_bounds__(256) void kt_cvt(const float* __restrict__ x,
                                              bf16* __restrict__ xb) {
  long i = ((long)blockIdx.x * 256 + threadIdx.x) * 8;
  f32x4 lo = *reinterpret_cast<const f32x4*>(x + i);
  f32x4 hi = *reinterpret_cast<const f32x4*>(x + i + 4);
  bf16x8 r;
#pragma unroll
  for (int q = 0; q < 4; ++q) { r[q] = (bf16)lo[q]; r[q + 4] = (bf16)hi[q]; }
  *reinterpret_cast<bf16x8*>(xb + i) = r;
}

// ---- dual 512x512 product: out = A-op @ (Bt-op)^T ; writes out and out+7 (transposed) ----
__global__ __launch_bounds__(512) void kt_mm2(
    bf16* __restrict__ Wm, int a0, int b0, int o0, int a1, int b1, int o1) {
  int aS = blockIdx.y ? a1 : a0;
  int bS = blockIdx.y ? b1 : b0;
  int oS = blockIdx.y ? o1 : o0;
  const bf16* A  = Wm + (long)aS * SLOT;
  const bf16* Bt = Wm + (long)bS * SLOT;
  bf16* O  = Wm + (long)oS * SLOT;
  bf16* Ot = Wm + (long)(oS + 7) * SLOT;
  const int tid = threadIdx.x;
  const int wave = tid >> 6, lane = tid & 63;
  const int quad = lane >> 4, l16 = lane & 15;
  const long rowbase = (long)blockIdx.x * 32;
  const int nbase = wave * 64;
  f32x4 acc[2][4] = {};
  for (int kk = 0; kk < Dm; kk += 32) {
    const int kf = kk + quad * 8;
    bf16x8 av0 = ld8(A + (rowbase + l16) * Dm + kf);
    bf16x8 av1 = ld8(A + (rowbase + 16 + l16) * Dm + kf);
#pragma unroll
    for (int nt = 0; nt < 4; ++nt) {
      bf16x8 bw = ld8(Bt + (long)(nbase + nt * 16 + l16) * Dm + kf);
      acc[0][nt] = mfma16(av0, bw, acc[0][nt]);
      acc[1][nt] = mfma16(av1, bw, acc[1][nt]);
    }
  }
#pragma unroll
  for (int mt = 0; mt < 2; ++mt)
#pragma unroll
    for (int nt = 0; nt < 4; ++nt)
#pragma unroll
      for (int r = 0; r < 4; ++r) {
        long m = rowbase + mt * 16 + quad * 4 + r;
        int n = nbase + nt * 16 + l16;
        float v = acc[mt][nt][r];
        O[m * Dm + n] = (bf16)v;
        Ot[(long)n * Dm + m] = (bf16)v;
      }
}

// ---- batched products, transposed-only output ----
struct Trip { int a, b, o; };
__device__ __constant__ Trip g_trips[20] = {
  {11, 40, 47},  // T^3t  = P8   * T^2t
  {35, 41, 48},  // T^12t = T^8  * T^4t
  {37, 43, 49},  // T^48t = T^32 * T^16t
  {39, 45, 50},  // T^192t= T^128* T^64t
  {2, 4, 51}, {19, 4, 52}, {20, 4, 53}, {21, 4, 54},   // Mt'_d = W_d * C
  {22, 4, 55}, {23, 4, 56}, {24, 4, 57}, {25, 4, 58},
  {1, 4, 59}, {5, 4, 60}, {6, 4, 61}, {7, 4, 62},      // Gt_j = P_{j+1} * C
  {8, 4, 63}, {9, 4, 64}, {10, 4, 65}, {11, 4, 66},
};
__global__ __launch_bounds__(512) void kt_mmbatch(bf16* __restrict__ Wm) {
  Trip t = g_trips[blockIdx.y];
  const bf16* A  = Wm + (long)t.a * SLOT;
  const bf16* Bt = Wm + (long)t.b * SLOT;
  bf16* Ot = Wm + (long)t.o * SLOT;
  const int tid = threadIdx.x;
  const int wave = tid >> 6, lane = tid & 63;
  const int quad = lane >> 4, l16 = lane & 15;
  const long rowbase = (long)blockIdx.x * 32;
  const int nbase = wave * 64;
  f32x4 acc[2][4] = {};
  for (int kk = 0; kk < Dm; kk += 32) {
    const int kf = kk + quad * 8;
    bf16x8 av0 = ld8(A + (rowbase + l16) * Dm + kf);
    bf16x8 av1 = ld8(A + (rowbase + 16 + l16) * Dm + kf);
#pragma unroll
    for (int nt = 0; nt < 4; ++nt) {
      bf16x8 bw = ld8(Bt + (long)(nbase + nt * 16 + l16) * Dm + kf);
      acc[0][nt] = mfma16(av0, bw, acc[0][nt]);
      acc[1][nt] = mfma16(av1, bw, acc[1][nt]);
    }
  }
#pragma unroll
  for (int mt = 0; mt < 2; ++mt)
#pragma unroll
    for (int nt = 0; nt < 4; ++nt)
#pragma unroll
      for (int r = 0; r < 4; ++r) {
        long m = rowbase + mt * 16 + quad * 4 + r;
        int n = nbase + nt * 16 + l16;
        Ot[(long)n * Dm + m] = (bf16)acc[mt][nt][r];
      }
}

// ---- chunk summaries: s_c = sum_i xb[m, 8c+i] @ W_{7-i}  (K-dim 8*512) ----
__global__ __launch_bounds__(512) void kt_summary(
    const bf16* __restrict__ xb, const bf16* __restrict__ Wm, bf16* __restrict__ H) {
  const int m = blockIdx.x;         // batch row
  const int c0 = blockIdx.y * 64;   // chunk tile
  const int tid = threadIdx.x;
  const int wave = tid >> 6, lane = tid & 63;
  const int quad = lane >> 4, l16 = lane & 15;
  const int nbase = wave * 64;
  f32x4 acc[4][4] = {};
  for (int i = 0; i < 8; ++i) {
    const bf16* Bt = Wm + (long)(i == 7 ? S_Bt : (S_Wt + 6 - i)) * SLOT;  // Wt_{7-i}
    for (int kk = 0; kk < Dm; kk += 32) {
      const int kf = kk + quad * 8;
      bf16x8 av[4];
#pragma unroll
      for (int mt = 0; mt < 4; ++mt) {
        int c = c0 + mt * 16 + l16;
        av[mt] = ld8(xb + ((long)m * Lseq + c * 8 + i) * Dm + kf);
      }
#pragma unroll
      for (int nt = 0; nt < 4; ++nt) {
        bf16x8 bw = ld8(Bt + (long)(nbase + nt * 16 + l16) * Dm + kf);
#pragma unroll
        for (int mt = 0; mt < 4; ++mt) acc[mt][nt] = mfma16(av[mt], bw, acc[mt][nt]);
      }
    }
  }
#pragma unroll
  for (int mt = 0; mt < 4; ++mt)
#pragma unroll
    for (int nt = 0; nt < 4; ++nt)
#pragma unroll
      for (int r = 0; r < 4; ++r) {
        int c = c0 + mt * 16 + quad * 4 + r;
        int n = nbase + nt * 16 + l16;
        H[((long)c * 32 + m) * Dm + n] = (bf16)acc[mt][nt][r];
      }
}

// ---- radix-4 Kogge-Stone round over chunk summaries ----
__global__ __launch_bounds__(512) void kt_ks4(
    const bf16* __restrict__ Hin, bf16* __restrict__ Hout,
    const bf16* __restrict__ Wm, int s, int b1, int b2, int b3) {
  const int c = blockIdx.x;
  const int tid = threadIdx.x;
  const int wave = tid >> 6, lane = tid & 63;
  const int quad = lane >> 4, l16 = lane & 15;
  const int nbase = wave * 64;
  int bs[3] = {b1, b2, b3};
  f32x4 acc[2][4] = {};
  for (int p = 1; p <= 3; ++p) {
    if (c - p * s < 0) break;
    const bf16* A  = Hin + (long)(c - p * s) * 32 * Dm;
    const bf16* Bt = Wm + (long)bs[p - 1] * SLOT;
    for (int kk = 0; kk < Dm; kk += 32) {
      const int kf = kk + quad * 8;
      bf16x8 av0 = ld8(A + (long)l16 * Dm + kf);
      bf16x8 av1 = ld8(A + (long)(16 + l16) * Dm + kf);
#pragma unroll
      for (int nt = 0; nt < 4; ++nt) {
        bf16x8 bw = ld8(Bt + (long)(nbase + nt * 16 + l16) * Dm + kf);
        acc[0][nt] = mfma16(av0, bw, acc[0][nt]);
        acc[1][nt] = mfma16(av1, bw, acc[1][nt]);
      }
    }
  }
#pragma unroll
  for (int mt = 0; mt < 2; ++mt)
#pragma unroll
    for (int nt = 0; nt < 4; ++nt)
#pragma unroll
      for (int r = 0; r < 4; ++r) {
        int m = mt * 16 + quad * 4 + r;
        int n = nbase + nt * 16 + l16;
        float v = acc[mt][nt][r] + (float)Hin[((long)c * 32 + m) * Dm + n];
        Hout[((long)c * 32 + m) * Dm + n] = (bf16)v;
      }
}

// ---- final: y_{m,8c+j} = sum_{d<=j} xb[m,8c+j-d] @ M'_d + g_c @ G_j ----
__global__ __launch_bounds__(512) void kt_conv(
    const bf16* __restrict__ xb, const bf16* __restrict__ Wm,
    const bf16* __restrict__ Hfin, float* __restrict__ y) {
  const int bid = blockIdx.x;       // 32 m * 4 cq * 8 j
  const int j = bid & 7;
  const int cq = (bid >> 3) & 3;
  const int m = bid >> 5;
  const int c0 = cq * 64;
  const int tid = threadIdx.x;
  const int wave = tid >> 6, lane = tid & 63;
  const int quad = lane >> 4, l16 = lane & 15;
  const int nbase = wave * 64;
  f32x4 acc[4][4] = {};
  for (int d = 0; d <= j; ++d) {
    const bf16* Bt = Wm + (long)(S_M + d) * SLOT;
    const int toff = j - d;
    for (int kk = 0; kk < Dm; kk += 32) {
      const int kf = kk + quad * 8;
      bf16x8 av[4];
#pragma unroll
      for (int mt = 0; mt < 4; ++mt) {
        int c = c0 + mt * 16 + l16;
        av[mt] = ld8(xb + ((long)m * Lseq + c * 8 + toff) * Dm + kf);
      }
#pragma unroll
      for (int nt = 0; nt < 4; ++nt) {
        bf16x8 bw = ld8(Bt + (long)(nbase + nt * 16 + l16) * Dm + kf);
#pragma unroll
        for (int mt = 0; mt < 4; ++mt) acc[mt][nt] = mfma16(av[mt], bw, acc[mt][nt]);
      }
    }
  }
  {  // g-term: g_c = Hfin[c-1] (zero for c==0)
    const bf16* Bt = Wm + (long)(S_G + j) * SLOT;
    for (int kk = 0; kk < Dm; kk += 32) {
      const int kf = kk + quad * 8;
      bf16x8 av[4];
#pragma unroll
      for (int mt = 0; mt < 4; ++mt) {
        int c = c0 + mt * 16 + l16;
        av[mt] = (c > 0) ? ld8(Hfin + ((long)(c - 1) * 32 + m) * Dm + kf) : zero8();
      }
#pragma unroll
      for (int nt = 0; nt < 4; ++nt) {
        bf16x8 bw = ld8(Bt + (long)(nbase + nt * 16 + l16) * Dm + kf);
#pragma unroll
        for (int mt = 0; mt < 4; ++mt) acc[mt][nt] = mfma16(av[mt], bw, acc[mt][nt]);
      }
    }
  }
#pragma unroll
  for (int mt = 0; mt < 4; ++mt)
#pragma unroll
    for (int nt = 0; nt < 4; ++nt)
#pragma unroll
      for (int r = 0; r < 4; ++r) {
        int c = c0 + mt * 16 + quad * 4 + r;
        int n = nbase + nt * 16 + l16;
        y[((long)m * Lseq + c * 8 + j) * Dm + n] = acc[mt][nt][r];
      }
}

extern "C" void kernel_launch(void* const* d_in, const int* in_sizes, int n_in,
                              void* d_out, int out_size, void* d_ws, size_t ws_size,
                              hipStream_t stream) {
  const float* x  = (const float*)d_in[0];
  const float* dA = (const float*)d_in[1];
  const float* dB = (const float*)d_in[2];
  const float* Cm = (const float*)d_in[3];
  float* out = (float*)d_out;

  char* w = (char*)d_ws;
  bf16* Wm = (bf16*)w; w += (long)NSLOT * SLOT * sizeof(bf16);      // 33.5 MB
  bf16* xb = (bf16*)w; w += (long)Bb * Lseq * Dm * sizeof(bf16);    // 64 MB
  bf16* H0 = (bf16*)w; w += (long)CH * 32 * Dm * sizeof(bf16);      // 8 MB
  bf16* H1 = (bf16*)w; w += (long)CH * 32 * Dm * sizeof(bf16);      // 8 MB

  kt_pack<<<dim3(Dm * Dm / 256, 3), 256, 0, stream>>>(dA, dB, Cm, Wm);
  kt_cvt<<<(Bb * Lseq * Dm / 8) / 256, 256, 0, stream>>>(x, xb);

  // chains: P_{k+1} = P_k A,  W_k = W_{k-1} A   (7 sequential dual launches)
  for (int k = 1; k <= 7; ++k)
    kt_mm2<<<dim3(16, 2), 512, 0, stream>>>(Wm,
        (k == 1 ? S_Abf : S_P + k - 2), S_At, S_P + k - 1,
        (k == 1 ? S_Bbf : S_W + k - 2), S_At, S_W + k - 1);
  // T-squaring chain: T^(2^k) (7 sequential), T = A^8 = P_8
  for (int k = 1; k <= 7; ++k)
    kt_mm2<<<dim3(16, 1), 512, 0, stream>>>(Wm,
        (k == 1 ? S_P + 6 : S_T + k - 2), (k == 1 ? S_Pt + 6 : S_Tt + k - 2),
        S_T + k - 1, 0, 0, 0);
  // batched: T^3,12,48,192 (t) + Mt'_d + Gt_j
  kt_mmbatch<<<dim3(16, 20), 512, 0, stream>>>(Wm);

  // chunk summaries
  kt_summary<<<dim3(32, 4), 512, 0, stream>>>(xb, Wm, H0);

  // radix-4 KS: shifts 1,4,16,64
  const int shifts[4] = {1, 4, 16, 64};
  const int bsl[4][3] = {{18, 40, 47}, {41, 42, 48}, {43, 44, 49}, {45, 46, 50}};
  bf16* hi = H0; bf16* ho = H1;
  for (int r = 0; r < 4; ++r) {
    kt_ks4<<<CH, 512, 0, stream>>>(hi, ho, Wm, shifts[r], bsl[r][0], bsl[r][1], bsl[r][2]);
    bf16* t = hi; hi = ho; ho = t;
  }
  // final prefixes in hi (== H0)

  // fused conv + output
  kt_conv<<<1024, 512, 0, stream>>>(xb, Wm, hi, out);
}